// Round 16
// baseline (64.367 us; speedup 1.0000x reference)
//
#include <hip/hip_runtime.h>

#define P_N 40000
#define M_N 100
#define NBF 10000   // k_fused blocks: 2 waves/block, 2 pillars/wave
#define NPART 80    // per-block partials: [0..44]=M2 corr, [45..53]=M1, [64..73]=R2 raw
#define NUSED 74

typedef _Float16 half2_t __attribute__((ext_vector_type(2)));

__device__ __forceinline__ float bcf(int x) { return __int_as_float(x); }
__device__ __forceinline__ int   bci(float x) { return __float_as_int(x); }
__device__ __forceinline__ float rlf(float v, int l) {
  return bcf(__builtin_amdgcn_readlane(bci(v), l));
}
__device__ __forceinline__ int pk16i(float a, float b) {
  return __builtin_bit_cast(int, __builtin_amdgcn_cvt_pkrtz(a, b));
}
__device__ __forceinline__ half2_t h2(int x) { return __builtin_bit_cast(half2_t, x); }
__device__ __forceinline__ float dot2(int a, int b, float acc) {
  return __builtin_amdgcn_fdot2(h2(a), h2(b), acc, false);
}

// DPP full-wave64 add-reduce on the VALU pipe. Lane 63 holds the sum.
__device__ __forceinline__ float dpp_sum64(float x) {
  x += bcf(__builtin_amdgcn_update_dpp(0, bci(x), 0x111, 0xf, 0xf, true)); // row_shr:1
  x += bcf(__builtin_amdgcn_update_dpp(0, bci(x), 0x112, 0xf, 0xf, true)); // row_shr:2
  x += bcf(__builtin_amdgcn_update_dpp(0, bci(x), 0x114, 0xf, 0xf, true)); // row_shr:4
  x += bcf(__builtin_amdgcn_update_dpp(0, bci(x), 0x118, 0xf, 0xf, true)); // row_shr:8
  x += bcf(__builtin_amdgcn_update_dpp(0, bci(x), 0x142, 0xf, 0xf, true)); // row_bcast:15
  x += bcf(__builtin_amdgcn_update_dpp(0, bci(x), 0x143, 0xf, 0xf, true)); // row_bcast:31
  return x;
}

// packed u for 2 points from feature-major packs: v_pk_fma_f16 chain
__device__ __forceinline__ half2_t uPK(int4 q, half2_t AA, half2_t BB,
                                       half2_t CC, half2_t DD, half2_t EE) {
  half2_t t = h2(q.w) * DD + EE;     // i01*DD + EE
  t = h2(q.z) * CC + t;              // + z01*CC
  t = h2(q.y) * BB + t;              // + y01*BB
  t = h2(q.x) * AA + t;              // + x01*AA
  return t;
}

// ---------------- Kernel 1 (fused) ----------------
// Mean-expansion formulation (verified r15): global accumulators = 10 raw
// products among {x,y,z,i} (valid-masked) + lane-indexed correction.
// umax: feature-major f16 packs staged in wave-private LDS; packed
// v_pk_fma_f16 + v_pk_max_f16 (2 points/instr, full-rate). gamma==1 -> umax only.

__global__ __launch_bounds__(128) void k_fused(
    const float* __restrict__ px, const float* __restrict__ py,
    const float* __restrict__ pz, const float* __restrict__ pi,
    const int* __restrict__ npp, const int* __restrict__ coors,
    const float* __restrict__ W,
    float* __restrict__ partials, float* __restrict__ umm)
{
  const int lane = threadIdx.x & 63;
  const int wid  = threadIdx.x >> 6;    // 0..1
  const int d    = lane;

  __shared__ int4  stage[2][2][64];     // [wave][pillar][pair] feature-major packs
  __shared__ float red[2][NPART];

  // ---- per-lane statistic assignment ----
  int c = 9, c2 = 9;                    // sentinel (lanes >= 54 idle)
  if (lane < 45) {
    int k = lane; c = 0;
    while (k >= 9 - c) { k -= 9 - c; ++c; }
    c2 = c + k;
  } else if (lane < 54) {
    c = lane - 45; c2 = 9;              // M1: pair with constant-1 feature
  }
  const int rc1 = (c  < 4) ? c  : (c  < 7) ? c  - 4 : (c  < 9) ? c  - 2 : 4;
  const int rc2 = (c2 < 4) ? c2 : (c2 < 7) ? c2 - 4 : (c2 < 9) ? c2 - 2 : 4;
  const bool bothVec = (rc1 < 4) && (rc2 < 4);
  const bool statln  = lane < 54;

  float w[9];
  #pragma unroll
  for (int q = 0; q < 9; ++q) w[q] = W[q * 64 + d];
  const float sA = w[0] + w[4], sB = w[1] + w[5], sC = w[2] + w[6], sD = w[3];
  const half2_t AA = h2(pk16i(sA, sA));
  const half2_t BB = h2(pk16i(sB, sB));
  const half2_t CC = h2(pk16i(sC, sC));
  const half2_t DD = h2(pk16i(sD, sD));
  const int H1 = 0x3C003C00;            // (1.0h, 1.0h)

  const bool act = lane < 50;
  const int wgid  = blockIdx.x * 2 + wid;
  const int pbase = __builtin_amdgcn_readfirstlane(wgid * 2);

  const int2 n2 = ((const int2*)npp)[wgid];
  int4 cc[2];
  cc[0] = ((const int4*)coors)[pbase + 0];
  cc[1] = ((const int4*)coors)[pbase + 1];

  // ---- load rows, pack to f16 (feature-major), stage to LDS ----
  int u0[2], u1[2], u2[2], u3[2];
  #pragma unroll
  for (int it = 0; it < 2; ++it) {
    const int p_ = pbase + it;
    float2 X = make_float2(0.f, 0.f), Y = X, Z = X, I = X;
    if (act) {
      X = ((const float2*)(px + (size_t)p_ * M_N))[lane];
      Y = ((const float2*)(py + (size_t)p_ * M_N))[lane];
      Z = ((const float2*)(pz + (size_t)p_ * M_N))[lane];
      I = ((const float2*)(pi + (size_t)p_ * M_N))[lane];
    }
    u0[it] = pk16i(X.x, X.y);
    u1[it] = pk16i(Y.x, Y.y);
    u2[it] = pk16i(Z.x, Z.y);
    u3[it] = pk16i(I.x, I.y);
    stage[wid][it][lane] = make_int4(u0[it], u1[it], u2[it], u3[it]);
  }

  float R2a[10] = {};
  float corrAcc = 0.f;

  #pragma unroll
  for (int it = 0; it < 2; ++it) {
    const int p_ = pbase + it;
    const int n  = ((const int*)&n2)[it];
    const float nf = (float)n;

    // validity mask for this lane's two point slots
    const unsigned msk = ((2 * lane     < n) ? 0x0000FFFFu : 0u)
                       | ((2 * lane + 1 < n) ? 0xFFFF0000u : 0u);
    const int g0 = u0[it] & msk;
    const int g1 = u1[it] & msk;
    const int g2 = u2[it] & msk;
    const int g3 = u3[it] & msk;

    // full sums (means) + valid sums: 7 DPP chains
    float fx = dot2(u0[it], H1, 0.f);
    float fy = dot2(u1[it], H1, 0.f);
    float fz = dot2(u2[it], H1, 0.f);
    float vx = dot2(g0, H1, 0.f);
    float vy = dot2(g1, H1, 0.f);
    float vz = dot2(g2, H1, 0.f);
    float vi = dot2(g3, H1, 0.f);
    fx = dpp_sum64(fx); fy = dpp_sum64(fy); fz = dpp_sum64(fz);
    vx = dpp_sum64(vx); vy = dpp_sum64(vy); vz = dpp_sum64(vz); vi = dpp_sum64(vi);

    const int nc = n < 1 ? 1 : n;
    const float inv = __builtin_amdgcn_rcpf((float)nc);
    const float mx = rlf(fx, 63) * inv;
    const float my = rlf(fy, 63) * inv;
    const float mz = rlf(fz, 63) * inv;
    const float svx = rlf(vx, 63);
    const float svy = rlf(vy, 63);
    const float svz = rlf(vz, 63);
    const float svi = rlf(vi, 63);

    const float xb = fmaf((float)cc[it].w, 0.16f, 0.08f);            // X0 = 0
    const float yb = fmaf((float)cc[it].z, 0.16f, 0.08f - 39.68f);   // Y0 = -39.68

    // 10 global raw products among x,y,z,i (valid-masked)
    R2a[0] = dot2(g0, g0, R2a[0]);
    R2a[1] = dot2(g0, g1, R2a[1]);
    R2a[2] = dot2(g0, g2, R2a[2]);
    R2a[3] = dot2(g0, g3, R2a[3]);
    R2a[4] = dot2(g1, g1, R2a[4]);
    R2a[5] = dot2(g1, g2, R2a[5]);
    R2a[6] = dot2(g1, g3, R2a[6]);
    R2a[7] = dot2(g2, g2, R2a[7]);
    R2a[8] = dot2(g2, g3, R2a[8]);
    R2a[9] = dot2(g3, g3, R2a[9]);

    // per-lane correction term
    {
      const float nxb = nf * xb, nyb = nf * yb;
      const float S1 = (rc1 == 0) ? svx : (rc1 == 1) ? svy : (rc1 == 2) ? svz
                     : (rc1 == 3) ? svi : (rc1 == 4) ? nf  : (rc1 == 5) ? nxb : nyb;
      const float S2 = (rc2 == 0) ? svx : (rc2 == 1) ? svy : (rc2 == 2) ? svz
                     : (rc2 == 3) ? svi : (rc2 == 4) ? nf  : (rc2 == 5) ? nxb : nyb;
      float base = 0.f;
      if (!bothVec)
        base = (rc1 > 3) ? ((rc1 == 4) ? S2 : (rc1 == 5) ? xb * S2 : yb * S2)
                         : ((rc2 == 4) ? S1 : (rc2 == 5) ? xb * S1 : yb * S1);
      const float mv1 = (c  == 4) ? mx : (c  == 5) ? my : (c  == 6) ? mz : 0.f;
      const float mv2 = (c2 == 4) ? mx : (c2 == 5) ? my : (c2 == 6) ? mz : 0.f;
      const float term = base - mv1 * S2 - mv2 * S1 + nf * mv1 * mv2;
      if (statln) corrAcc += term;
    }

    // per-pillar constant term of the linear output
    const float sE = fmaf(-mx, w[4], fmaf(-my, w[5], fmaf(-mz, w[6],
                     fmaf(xb, w[7], yb * w[8]))));
    const half2_t EE = h2(pk16i(sE, sE));

    // ---- umax: packed fma/max over feature-major LDS packs ----
    const int4* sp = &stage[wid][it][0];
    half2_t ap0 = h2((int)0xFC00FC00);   // (-inf, -inf)
    half2_t ap1 = ap0;
    const int nh = n >> 1;               // full point-pairs
    int l = 0;
    for (; l + 2 <= nh; l += 2) {        // uniform (SGPR) trip count
      const int4 qa = sp[l];
      const int4 qb = sp[l + 1];
      ap0 = __builtin_elementwise_max(ap0, uPK(qa, AA, BB, CC, DD, EE));
      ap1 = __builtin_elementwise_max(ap1, uPK(qb, AA, BB, CC, DD, EE));
    }
    if (l < nh)
      ap0 = __builtin_elementwise_max(ap0, uPK(sp[l], AA, BB, CC, DD, EE));
    const half2_t am = __builtin_elementwise_max(ap0, ap1);
    float um = fmaxf((float)am.x, (float)am.y);
    if (n & 1) {                          // last point: lo halves of pair nh
      const int4 qt = sp[nh];
      const float tx = (float)h2(qt.x).x;
      const float ty = (float)h2(qt.y).x;
      const float tz = (float)h2(qt.z).x;
      const float ti = (float)h2(qt.w).x;
      um = fmaxf(um, fmaf(tx, sA, fmaf(ty, sB, fmaf(tz, sC, fmaf(ti, sD, sE)))));
    }
    umm[(size_t)p_ * 64 + d] = um;
  }

  // ---- epilogue: 10 chains for R2, lane-indexed corr, block reduce ----
  #pragma unroll
  for (int i = 0; i < 10; ++i) R2a[i] = dpp_sum64(R2a[i]);

  red[wid][lane] = corrAcc;              // lanes >=54 wrote 0
  if (lane == 63) {
    #pragma unroll
    for (int i = 0; i < 10; ++i) red[wid][64 + i] = R2a[i];
  }
  __syncthreads();
  if (threadIdx.x < NUSED) {
    const int t = threadIdx.x;
    partials[blockIdx.x * NPART + t] = red[0][t] + red[1][t];
  }
}

// ---------------- Kernel 1b: reduce partials -> 74 stats ----------------

__global__ __launch_bounds__(256) void k_red(
    const float* __restrict__ partials, float* __restrict__ stats)
{
  const int c = blockIdx.x;              // 0..73
  float s = 0.f;
  for (int b = threadIdx.x; b < NBF; b += 256) s += partials[b * NPART + c];
  s = dpp_sum64(s);
  __shared__ float r4[4];
  const int lane = threadIdx.x & 63, wid = threadIdx.x >> 6;
  if (lane == 63) r4[wid] = s;
  __syncthreads();
  if (threadIdx.x == 0) stats[c] = r4[0] + r4[1] + r4[2] + r4[3];
}

// ---------------- Kernel 2: stats -> per-channel BN scale/shift ----------------

__global__ __launch_bounds__(64) void k_stats(
    const float* __restrict__ stats, const float* __restrict__ W,
    const float* __restrict__ gamma, const float* __restrict__ beta,
    float* __restrict__ scale, float* __restrict__ shift)
{
  const int d = threadIdx.x;
  __shared__ float Cs[NUSED];
  Cs[d] = stats[d];
  if (d < NUSED - 64) Cs[64 + d] = stats[64 + d];
  __syncthreads();

  // assemble mom1[9], mom2[45]
  float mom1[9];
  #pragma unroll
  for (int q = 0; q < 9; ++q) mom1[q] = Cs[45 + q];
  float mom2[45];
  {
    int k = 0;
    #pragma unroll
    for (int cA = 0; cA < 9; ++cA) {
      #pragma unroll
      for (int cB = cA; cB < 9; ++cB) {
        float v = Cs[k];
        if (cA <= 6 && cB <= 6) {
          const int a = (cA < 4) ? cA : cA - 4;
          const int b = (cB < 4) ? cB : cB - 4;
          const int lo = a < b ? a : b;
          const int hi = a < b ? b : a;
          const int idx = lo * 4 - lo * (lo - 1) / 2 + (hi - lo);
          v += Cs[64 + idx];
        }
        mom2[k] = v;
        ++k;
      }
    }
  }

  float w[9];
  #pragma unroll
  for (int q = 0; q < 9; ++q) w[q] = W[q * 64 + d];
  const float invN = 1.f / ((float)P_N * (float)M_N);
  float mu = 0.f;
  #pragma unroll
  for (int q = 0; q < 9; ++q) mu += mom1[q] * w[q];
  mu *= invN;
  float e2 = 0.f;
  int k = 0;
  #pragma unroll
  for (int cA = 0; cA < 9; ++cA) {
    #pragma unroll
    for (int cB = cA; cB < 9; ++cB) {
      const float t = w[cA] * w[cB] * mom2[k];
      e2 += (cA == cB) ? t : 2.f * t;
      ++k;
    }
  }
  e2 *= invN;
  float var = e2 - mu * mu;
  var = var < 0.f ? 0.f : var;
  const float sc = gamma[d] * rsqrtf(var + 1e-5f);
  const float sh = fmaf(-mu, sc, beta[d]);
  scale[d] = sc;
  shift[d] = sh;
}

// ---------------- Kernel 3: finalize in place ----------------

__global__ __launch_bounds__(256) void k_apply(
    const int* __restrict__ npp, const float* __restrict__ scale,
    const float* __restrict__ shift, float* __restrict__ out)
{
  const int gid = blockIdx.x * 256 + threadIdx.x;   // 0 .. P_N*64/4 - 1
  const int p = gid >> 4;
  const int q = gid & 15;

  float4 u4 = ((const float4*)out)[gid];
  const float4 sc4 = ((const float4*)scale)[q];
  const float4 sh4 = ((const float4*)shift)[q];
  const int n = npp[p];
  const bool has_masked = n < M_N;

  float4 r;
  float t;
  t = fmaf(sc4.x, u4.x, sh4.x); if (has_masked) t = fmaxf(t, sh4.x); r.x = fmaxf(t, 0.f);
  t = fmaf(sc4.y, u4.y, sh4.y); if (has_masked) t = fmaxf(t, sh4.y); r.y = fmaxf(t, 0.f);
  t = fmaf(sc4.z, u4.z, sh4.z); if (has_masked) t = fmaxf(t, sh4.z); r.z = fmaxf(t, 0.f);
  t = fmaf(sc4.w, u4.w, sh4.w); if (has_masked) t = fmaxf(t, sh4.w); r.w = fmaxf(t, 0.f);
  ((float4*)out)[gid] = r;
}

// ---------------- launch ----------------

extern "C" void kernel_launch(void* const* d_in, const int* in_sizes, int n_in,
                              void* d_out, int out_size, void* d_ws, size_t ws_size,
                              hipStream_t stream) {
  const float* px    = (const float*)d_in[0];
  const float* py    = (const float*)d_in[1];
  const float* pz    = (const float*)d_in[2];
  const float* pi    = (const float*)d_in[3];
  const int*   npp   = (const int*)d_in[4];
  const int*   coors = (const int*)d_in[5];
  const float* W     = (const float*)d_in[6];
  const float* gamma = (const float*)d_in[7];
  const float* beta  = (const float*)d_in[8];
  float* out = (float*)d_out;

  float* wsf      = (float*)d_ws;
  float* partials = wsf;                    // NBF*NPART = 800000 floats
  float* stats    = wsf + 800000;           // 74
  float* scale    = wsf + 800128;           // 64
  float* shift    = wsf + 800192;           // 64

  k_fused<<<NBF, 128, 0, stream>>>(px, py, pz, pi, npp, coors, W, partials, out);
  k_red<<<NUSED, 256, 0, stream>>>(partials, stats);
  k_stats<<<1, 64, 0, stream>>>(stats, W, gamma, beta, scale, shift);
  k_apply<<<P_N * 64 / 4 / 256, 256, 0, stream>>>(npp, scale, shift, out);
}

// Round 17
// 58.376 us; speedup vs baseline: 1.1026x; 1.1026x over previous
//
#include <hip/hip_runtime.h>

#define P_N 40000
#define M_N 100
#define NBF 10000   // k_fused blocks: 2 waves/block, 2 pillars/wave
#define NPART 80    // per-bucket stats: [0..44]=M2 corr, [45..53]=M1, [64..73]=R2 raw
#define NUSED 74
#define NBUCKET 32

typedef _Float16 half2_t __attribute__((ext_vector_type(2)));

__device__ __forceinline__ float bcf(int x) { return __int_as_float(x); }
__device__ __forceinline__ int   bci(float x) { return __float_as_int(x); }
__device__ __forceinline__ float rlf(float v, int l) {
  return bcf(__builtin_amdgcn_readlane(bci(v), l));
}
__device__ __forceinline__ int pk16i(float a, float b) {
  return __builtin_bit_cast(int, __builtin_amdgcn_cvt_pkrtz(a, b));
}
__device__ __forceinline__ half2_t h2(int x) { return __builtin_bit_cast(half2_t, x); }
__device__ __forceinline__ float dot2(int a, int b, float acc) {
  return __builtin_amdgcn_fdot2(h2(a), h2(b), acc, false);
}

// DPP full-wave64 add-reduce on the VALU pipe. Lane 63 holds the sum.
__device__ __forceinline__ float dpp_sum64(float x) {
  x += bcf(__builtin_amdgcn_update_dpp(0, bci(x), 0x111, 0xf, 0xf, true)); // row_shr:1
  x += bcf(__builtin_amdgcn_update_dpp(0, bci(x), 0x112, 0xf, 0xf, true)); // row_shr:2
  x += bcf(__builtin_amdgcn_update_dpp(0, bci(x), 0x114, 0xf, 0xf, true)); // row_shr:4
  x += bcf(__builtin_amdgcn_update_dpp(0, bci(x), 0x118, 0xf, 0xf, true)); // row_shr:8
  x += bcf(__builtin_amdgcn_update_dpp(0, bci(x), 0x142, 0xf, 0xf, true)); // row_bcast:15
  x += bcf(__builtin_amdgcn_update_dpp(0, bci(x), 0x143, 0xf, 0xf, true)); // row_bcast:31
  return x;
}

// packed u for 2 points from feature-major packs: v_pk_fma_f16 chain
__device__ __forceinline__ half2_t uPK(int4 q, half2_t AA, half2_t BB,
                                       half2_t CC, half2_t DD, half2_t EE) {
  half2_t t = h2(q.w) * DD + EE;     // i01*DD + EE
  t = h2(q.z) * CC + t;              // + z01*CC
  t = h2(q.y) * BB + t;              // + y01*BB
  t = h2(q.x) * AA + t;              // + x01*AA
  return t;
}

// ---------------- Kernel 0: zero the atomic buckets ----------------

__global__ __launch_bounds__(256) void k_zero(float* __restrict__ buckets) {
  const int i = threadIdx.x;
  #pragma unroll
  for (int k = 0; k < NBUCKET * NPART / 256; ++k) buckets[k * 256 + i] = 0.f;
}

// ---------------- Kernel 1 (fused) ----------------
// Mean-expansion formulation (verified r15): global accumulators = 10 raw
// products among {x,y,z,i} (valid-masked) + lane-indexed correction.
// umax: feature-major f16 packs in wave-private LDS; v_pk_fma/_max (r16, 49.5us).
// Epilogue: bucketed atomicAdd (replaces r16's k_red strided reduction).

__global__ __launch_bounds__(128) void k_fused(
    const float* __restrict__ px, const float* __restrict__ py,
    const float* __restrict__ pz, const float* __restrict__ pi,
    const int* __restrict__ npp, const int* __restrict__ coors,
    const float* __restrict__ W,
    float* __restrict__ buckets, float* __restrict__ umm)
{
  const int lane = threadIdx.x & 63;
  const int wid  = threadIdx.x >> 6;    // 0..1
  const int d    = lane;

  __shared__ int4  stage[2][2][64];     // [wave][pillar][pair] feature-major packs
  __shared__ float red[2][NPART];

  // ---- per-lane statistic assignment ----
  int c = 9, c2 = 9;                    // sentinel (lanes >= 54 idle)
  if (lane < 45) {
    int k = lane; c = 0;
    while (k >= 9 - c) { k -= 9 - c; ++c; }
    c2 = c + k;
  } else if (lane < 54) {
    c = lane - 45; c2 = 9;              // M1: pair with constant-1 feature
  }
  const int rc1 = (c  < 4) ? c  : (c  < 7) ? c  - 4 : (c  < 9) ? c  - 2 : 4;
  const int rc2 = (c2 < 4) ? c2 : (c2 < 7) ? c2 - 4 : (c2 < 9) ? c2 - 2 : 4;
  const bool bothVec = (rc1 < 4) && (rc2 < 4);
  const bool statln  = lane < 54;

  float w[9];
  #pragma unroll
  for (int q = 0; q < 9; ++q) w[q] = W[q * 64 + d];
  const float sA = w[0] + w[4], sB = w[1] + w[5], sC = w[2] + w[6], sD = w[3];
  const half2_t AA = h2(pk16i(sA, sA));
  const half2_t BB = h2(pk16i(sB, sB));
  const half2_t CC = h2(pk16i(sC, sC));
  const half2_t DD = h2(pk16i(sD, sD));
  const int H1 = 0x3C003C00;            // (1.0h, 1.0h)

  const bool act = lane < 50;
  const int wgid  = blockIdx.x * 2 + wid;
  const int pbase = __builtin_amdgcn_readfirstlane(wgid * 2);

  const int2 n2 = ((const int2*)npp)[wgid];
  int4 cc[2];
  cc[0] = ((const int4*)coors)[pbase + 0];
  cc[1] = ((const int4*)coors)[pbase + 1];

  // ---- load rows, pack to f16 (feature-major), stage to LDS ----
  int u0[2], u1[2], u2[2], u3[2];
  #pragma unroll
  for (int it = 0; it < 2; ++it) {
    const int p_ = pbase + it;
    float2 X = make_float2(0.f, 0.f), Y = X, Z = X, I = X;
    if (act) {
      X = ((const float2*)(px + (size_t)p_ * M_N))[lane];
      Y = ((const float2*)(py + (size_t)p_ * M_N))[lane];
      Z = ((const float2*)(pz + (size_t)p_ * M_N))[lane];
      I = ((const float2*)(pi + (size_t)p_ * M_N))[lane];
    }
    u0[it] = pk16i(X.x, X.y);
    u1[it] = pk16i(Y.x, Y.y);
    u2[it] = pk16i(Z.x, Z.y);
    u3[it] = pk16i(I.x, I.y);
    stage[wid][it][lane] = make_int4(u0[it], u1[it], u2[it], u3[it]);
  }

  float R2a[10] = {};
  float corrAcc = 0.f;

  #pragma unroll
  for (int it = 0; it < 2; ++it) {
    const int p_ = pbase + it;
    const int n  = ((const int*)&n2)[it];
    const float nf = (float)n;

    // validity mask for this lane's two point slots
    const unsigned msk = ((2 * lane     < n) ? 0x0000FFFFu : 0u)
                       | ((2 * lane + 1 < n) ? 0xFFFF0000u : 0u);
    const int g0 = u0[it] & msk;
    const int g1 = u1[it] & msk;
    const int g2 = u2[it] & msk;
    const int g3 = u3[it] & msk;

    // full sums (means) + valid sums: 7 DPP chains
    float fx = dot2(u0[it], H1, 0.f);
    float fy = dot2(u1[it], H1, 0.f);
    float fz = dot2(u2[it], H1, 0.f);
    float vx = dot2(g0, H1, 0.f);
    float vy = dot2(g1, H1, 0.f);
    float vz = dot2(g2, H1, 0.f);
    float vi = dot2(g3, H1, 0.f);
    fx = dpp_sum64(fx); fy = dpp_sum64(fy); fz = dpp_sum64(fz);
    vx = dpp_sum64(vx); vy = dpp_sum64(vy); vz = dpp_sum64(vz); vi = dpp_sum64(vi);

    const int nc = n < 1 ? 1 : n;
    const float inv = __builtin_amdgcn_rcpf((float)nc);
    const float mx = rlf(fx, 63) * inv;
    const float my = rlf(fy, 63) * inv;
    const float mz = rlf(fz, 63) * inv;
    const float svx = rlf(vx, 63);
    const float svy = rlf(vy, 63);
    const float svz = rlf(vz, 63);
    const float svi = rlf(vi, 63);

    const float xb = fmaf((float)cc[it].w, 0.16f, 0.08f);            // X0 = 0
    const float yb = fmaf((float)cc[it].z, 0.16f, 0.08f - 39.68f);   // Y0 = -39.68

    // 10 global raw products among x,y,z,i (valid-masked)
    R2a[0] = dot2(g0, g0, R2a[0]);
    R2a[1] = dot2(g0, g1, R2a[1]);
    R2a[2] = dot2(g0, g2, R2a[2]);
    R2a[3] = dot2(g0, g3, R2a[3]);
    R2a[4] = dot2(g1, g1, R2a[4]);
    R2a[5] = dot2(g1, g2, R2a[5]);
    R2a[6] = dot2(g1, g3, R2a[6]);
    R2a[7] = dot2(g2, g2, R2a[7]);
    R2a[8] = dot2(g2, g3, R2a[8]);
    R2a[9] = dot2(g3, g3, R2a[9]);

    // per-lane correction term
    {
      const float nxb = nf * xb, nyb = nf * yb;
      const float S1 = (rc1 == 0) ? svx : (rc1 == 1) ? svy : (rc1 == 2) ? svz
                     : (rc1 == 3) ? svi : (rc1 == 4) ? nf  : (rc1 == 5) ? nxb : nyb;
      const float S2 = (rc2 == 0) ? svx : (rc2 == 1) ? svy : (rc2 == 2) ? svz
                     : (rc2 == 3) ? svi : (rc2 == 4) ? nf  : (rc2 == 5) ? nxb : nyb;
      float base = 0.f;
      if (!bothVec)
        base = (rc1 > 3) ? ((rc1 == 4) ? S2 : (rc1 == 5) ? xb * S2 : yb * S2)
                         : ((rc2 == 4) ? S1 : (rc2 == 5) ? xb * S1 : yb * S1);
      const float mv1 = (c  == 4) ? mx : (c  == 5) ? my : (c  == 6) ? mz : 0.f;
      const float mv2 = (c2 == 4) ? mx : (c2 == 5) ? my : (c2 == 6) ? mz : 0.f;
      const float term = base - mv1 * S2 - mv2 * S1 + nf * mv1 * mv2;
      if (statln) corrAcc += term;
    }

    // per-pillar constant term of the linear output
    const float sE = fmaf(-mx, w[4], fmaf(-my, w[5], fmaf(-mz, w[6],
                     fmaf(xb, w[7], yb * w[8]))));
    const half2_t EE = h2(pk16i(sE, sE));

    // ---- umax: packed fma/max over feature-major LDS packs ----
    const int4* sp = &stage[wid][it][0];
    half2_t ap0 = h2((int)0xFC00FC00);   // (-inf, -inf)
    half2_t ap1 = ap0;
    const int nh = n >> 1;               // full point-pairs
    int l = 0;
    for (; l + 2 <= nh; l += 2) {        // uniform (SGPR) trip count
      const int4 qa = sp[l];
      const int4 qb = sp[l + 1];
      ap0 = __builtin_elementwise_max(ap0, uPK(qa, AA, BB, CC, DD, EE));
      ap1 = __builtin_elementwise_max(ap1, uPK(qb, AA, BB, CC, DD, EE));
    }
    if (l < nh)
      ap0 = __builtin_elementwise_max(ap0, uPK(sp[l], AA, BB, CC, DD, EE));
    const half2_t am = __builtin_elementwise_max(ap0, ap1);
    float um = fmaxf((float)am.x, (float)am.y);
    if (n & 1) {                          // last point: lo halves of pair nh
      const int4 qt = sp[nh];
      const float tx = (float)h2(qt.x).x;
      const float ty = (float)h2(qt.y).x;
      const float tz = (float)h2(qt.z).x;
      const float ti = (float)h2(qt.w).x;
      um = fmaxf(um, fmaf(tx, sA, fmaf(ty, sB, fmaf(tz, sC, fmaf(ti, sD, sE)))));
    }
    umm[(size_t)p_ * 64 + d] = um;
  }

  // ---- epilogue: 10 chains for R2, block reduce, bucketed atomicAdd ----
  #pragma unroll
  for (int i = 0; i < 10; ++i) R2a[i] = dpp_sum64(R2a[i]);

  red[wid][lane] = corrAcc;              // lanes >=54 wrote 0
  if (lane == 63) {
    #pragma unroll
    for (int i = 0; i < 10; ++i) red[wid][64 + i] = R2a[i];
  }
  __syncthreads();
  if (threadIdx.x < NUSED) {
    const int t = threadIdx.x;
    atomicAdd(&buckets[(blockIdx.x & (NBUCKET - 1)) * NPART + t],
              red[0][t] + red[1][t]);
  }
}

// ---------------- Kernel 2: buckets -> per-channel BN scale/shift ----------------

__global__ __launch_bounds__(64) void k_stats(
    const float* __restrict__ buckets, const float* __restrict__ W,
    const float* __restrict__ gamma, const float* __restrict__ beta,
    float* __restrict__ scale, float* __restrict__ shift)
{
  const int d = threadIdx.x;
  __shared__ float Cs[NUSED];
  {
    float s0 = 0.f, s1 = 0.f;
    #pragma unroll
    for (int b = 0; b < NBUCKET; ++b) {
      s0 += buckets[b * NPART + d];
      if (d < NUSED - 64) s1 += buckets[b * NPART + 64 + d];
    }
    Cs[d] = s0;
    if (d < NUSED - 64) Cs[64 + d] = s1;
  }
  __syncthreads();

  // assemble mom1[9], mom2[45]
  float mom1[9];
  #pragma unroll
  for (int q = 0; q < 9; ++q) mom1[q] = Cs[45 + q];
  float mom2[45];
  {
    int k = 0;
    #pragma unroll
    for (int cA = 0; cA < 9; ++cA) {
      #pragma unroll
      for (int cB = cA; cB < 9; ++cB) {
        float v = Cs[k];
        if (cA <= 6 && cB <= 6) {
          const int a = (cA < 4) ? cA : cA - 4;
          const int b = (cB < 4) ? cB : cB - 4;
          const int lo = a < b ? a : b;
          const int hi = a < b ? b : a;
          const int idx = lo * 4 - lo * (lo - 1) / 2 + (hi - lo);
          v += Cs[64 + idx];
        }
        mom2[k] = v;
        ++k;
      }
    }
  }

  float w[9];
  #pragma unroll
  for (int q = 0; q < 9; ++q) w[q] = W[q * 64 + d];
  const float invN = 1.f / ((float)P_N * (float)M_N);
  float mu = 0.f;
  #pragma unroll
  for (int q = 0; q < 9; ++q) mu += mom1[q] * w[q];
  mu *= invN;
  float e2 = 0.f;
  int k = 0;
  #pragma unroll
  for (int cA = 0; cA < 9; ++cA) {
    #pragma unroll
    for (int cB = cA; cB < 9; ++cB) {
      const float t = w[cA] * w[cB] * mom2[k];
      e2 += (cA == cB) ? t : 2.f * t;
      ++k;
    }
  }
  e2 *= invN;
  float var = e2 - mu * mu;
  var = var < 0.f ? 0.f : var;
  const float sc = gamma[d] * rsqrtf(var + 1e-5f);
  const float sh = fmaf(-mu, sc, beta[d]);
  scale[d] = sc;
  shift[d] = sh;
}

// ---------------- Kernel 3: finalize in place ----------------

__global__ __launch_bounds__(256) void k_apply(
    const int* __restrict__ npp, const float* __restrict__ scale,
    const float* __restrict__ shift, float* __restrict__ out)
{
  const int gid = blockIdx.x * 256 + threadIdx.x;   // 0 .. P_N*64/4 - 1
  const int p = gid >> 4;
  const int q = gid & 15;

  float4 u4 = ((const float4*)out)[gid];
  const float4 sc4 = ((const float4*)scale)[q];
  const float4 sh4 = ((const float4*)shift)[q];
  const int n = npp[p];
  const bool has_masked = n < M_N;

  float4 r;
  float t;
  t = fmaf(sc4.x, u4.x, sh4.x); if (has_masked) t = fmaxf(t, sh4.x); r.x = fmaxf(t, 0.f);
  t = fmaf(sc4.y, u4.y, sh4.y); if (has_masked) t = fmaxf(t, sh4.y); r.y = fmaxf(t, 0.f);
  t = fmaf(sc4.z, u4.z, sh4.z); if (has_masked) t = fmaxf(t, sh4.z); r.z = fmaxf(t, 0.f);
  t = fmaf(sc4.w, u4.w, sh4.w); if (has_masked) t = fmaxf(t, sh4.w); r.w = fmaxf(t, 0.f);
  ((float4*)out)[gid] = r;
}

// ---------------- launch ----------------

extern "C" void kernel_launch(void* const* d_in, const int* in_sizes, int n_in,
                              void* d_out, int out_size, void* d_ws, size_t ws_size,
                              hipStream_t stream) {
  const float* px    = (const float*)d_in[0];
  const float* py    = (const float*)d_in[1];
  const float* pz    = (const float*)d_in[2];
  const float* pi    = (const float*)d_in[3];
  const int*   npp   = (const int*)d_in[4];
  const int*   coors = (const int*)d_in[5];
  const float* W     = (const float*)d_in[6];
  const float* gamma = (const float*)d_in[7];
  const float* beta  = (const float*)d_in[8];
  float* out = (float*)d_out;

  float* wsf     = (float*)d_ws;
  float* buckets = wsf;                     // NBUCKET*NPART = 2560 floats
  float* scale   = wsf + 2560;              // 64
  float* shift   = wsf + 2624;              // 64

  k_zero<<<1, 256, 0, stream>>>(buckets);
  k_fused<<<NBF, 128, 0, stream>>>(px, py, pz, pi, npp, coors, W, buckets, out);
  k_stats<<<1, 64, 0, stream>>>(buckets, W, gamma, beta, scale, shift);
  k_apply<<<P_N * 64 / 4 / 256, 256, 0, stream>>>(npp, scale, shift, out);
}